// Round 8
// baseline (54.633 us; speedup 1.0000x reference)
//
#include <hip/hip_runtime.h>

#define B_ 2
#define N_ 2048
#define M_ 2048
#define D_ 256
#define H_ 8
#define DH_ 32
#define SPLITS 2
// 1/sqrt(32) * log2(e): fold into q projection; attention works in exp2 domain
#define QSCALE (0.17677669529663689f * 1.4426950408889634f)

typedef __attribute__((ext_vector_type(8))) short short8;
typedef __attribute__((ext_vector_type(4))) float f32x4;
typedef unsigned short u16;
typedef unsigned int u32;

#if __has_builtin(__builtin_amdgcn_exp2f)
#define EXP2 __builtin_amdgcn_exp2f
#else
#define EXP2 exp2f
#endif

__device__ __forceinline__ u16 f2bf(float f) {
  u32 u = __float_as_uint(f);
  return (u16)((u + 0x7fffu + ((u >> 16) & 1u)) >> 16);  // RNE
}
__device__ __forceinline__ u32 cvtpk_bf16(float lo, float hi) {
  u32 r;
  asm("v_cvt_pk_bf16_f32 %0, %1, %2" : "=v"(r) : "v"(lo), "v"(hi));
  return r;
}
__device__ __forceinline__ void gload_lds16(const u16* g, u16* l) {
  __builtin_amdgcn_global_load_lds((const __attribute__((address_space(1))) void*)g,
                                   (__attribute__((address_space(3))) void*)l, 16, 0, 0);
}
__device__ __forceinline__ void gload_lds16f(const float* g, float* l) {
  __builtin_amdgcn_global_load_lds((const __attribute__((address_space(1))) void*)g,
                                   (__attribute__((address_space(3))) void*)l, 16, 0, 0);
}

// ---------- K0: convert W (f32 [k][c]) -> W^T (bf16 [c][k]), once ----------
// grid = 4 matrices x 16 tiles of 64x64 (round-3 verified code path).
__global__ __launch_bounds__(256) void wtconv_kernel(
    const float* __restrict__ Wq, const float* __restrict__ Wk,
    const float* __restrict__ Wv, const float* __restrict__ Wo,
    u16* __restrict__ wTq, u16* __restrict__ wTk, u16* __restrict__ wTv,
    u16* __restrict__ wTo) {
  __shared__ u16 sh[64][72];
  const int blk = blockIdx.x;
  const int mi = blk >> 4, tile = blk & 15;
  const float* Ws = mi == 0 ? Wq : mi == 1 ? Wk : mi == 2 ? Wv : Wo;
  u16* Wd = mi == 0 ? wTq : mi == 1 ? wTk : mi == 2 ? wTv : wTo;
  const int r0 = (tile >> 2) * 64, c0 = (tile & 3) * 64;
  const int r = threadIdx.x & 63, qt = threadIdx.x >> 6;
  const float* sp = Ws + (size_t)(r0 + r) * D_ + c0 + qt * 16;
  u32 w[8];
#pragma unroll
  for (int i = 0; i < 4; ++i) {
    f32x4 v = *(const f32x4*)(sp + i * 4);
    w[i * 2 + 0] = cvtpk_bf16(v[0], v[1]);
    w[i * 2 + 1] = cvtpk_bf16(v[2], v[3]);
  }
  *(uint4*)(&sh[r][qt * 16]) = *(uint4*)&w[0];
  *(uint4*)(&sh[r][qt * 16 + 8]) = *(uint4*)&w[4];
  __syncthreads();
  const int cc = threadIdx.x & 63;
  u32 t2[8];
#pragma unroll
  for (int i = 0; i < 8; ++i) {
    u32 lo = sh[qt * 16 + 2 * i][cc];
    u32 hi = sh[qt * 16 + 2 * i + 1][cc];
    t2[i] = lo | (hi << 16);
  }
  u16* op = Wd + (size_t)(c0 + cc) * D_ + r0 + qt * 16;
  *(uint4*)op = *(uint4*)&t2[0];
  *(uint4*)(op + 8) = *(uint4*)&t2[4];
}

// ---------- K1: q/k/v projection: X staged (LDS bf16), W^T frags from global ----
// block = 16 n-rows x 256 cols, 4 waves (wave = 64 c x 16 n). Grid (256, 3).
__global__ __launch_bounds__(256, 4) void qkvproj_kernel(
    const float* __restrict__ Xq, const float* __restrict__ Xk, const float* __restrict__ Xv,
    const u16* __restrict__ wTq, const u16* __restrict__ wTk, const u16* __restrict__ wTv,
    const float* __restrict__ bq, const float* __restrict__ bk, const float* __restrict__ bv,
    u16* __restrict__ qb, u16* __restrict__ kb, u16* __restrict__ vtb) {
  __shared__ u16 xs[16 * 256];  // [n][k] bf16, 16B-slot swizzle (k>>3)^(n&7)
  const int p = blockIdx.y;
  const int n0 = blockIdx.x * 16;
  const float* X = p == 0 ? Xq : (p == 1 ? Xk : Xv);
  const u16* wT = p == 0 ? wTq : (p == 1 ? wTk : wTv);
  const float* bias = p == 0 ? bq : (p == 1 ? bk : bv);
  const int t = threadIdx.x;

  {  // stage X: per thread 16 f32 (row t>>4, k (t&15)*16)
    const int nL = t >> 4, kc = (t & 15) * 16;
    const float* xp = X + (size_t)(n0 + nL) * D_ + kc;
#pragma unroll
    for (int m = 0; m < 2; ++m) {
      const f32x4 a = *(const f32x4*)(xp + 8 * m);
      const f32x4 b2 = *(const f32x4*)(xp + 8 * m + 4);
      uint4 v;
      v.x = cvtpk_bf16(a[0], a[1]);
      v.y = cvtpk_bf16(a[2], a[3]);
      v.z = cvtpk_bf16(b2[0], b2[1]);
      v.w = cvtpk_bf16(b2[2], b2[3]);
      const int k0 = kc + 8 * m;
      *(uint4*)(xs + nL * 256 + (((k0 >> 3) ^ (nL & 7)) * 8)) = v;
    }
  }
  __syncthreads();

  const int wv = t >> 6, lane = t & 63, lr = lane & 15, lg = lane >> 4;
  const int c0 = wv * 64;
  const f32x4 zz = {0.f, 0.f, 0.f, 0.f};
  f32x4 acc[4] = {zz, zz, zz, zz};
#pragma unroll
  for (int ks = 0; ks < 8; ++ks) {
    const short8 a = *(const short8*)(xs + lr * 256 + (((ks * 4 + lg) ^ (lr & 7)) * 8));
#pragma unroll
    for (int ct = 0; ct < 4; ++ct) {
      const short8 b = *(const short8*)(wT + (size_t)(c0 + ct * 16 + lr) * D_ + ks * 32 + lg * 8);
      acc[ct] = __builtin_amdgcn_mfma_f32_16x16x32_bf16(a, b, acc[ct], 0, 0, 0);
    }
  }

  // C layout: col(lr)=c, row(lg*4+j)=n
  const int bidx = n0 >> 11;
  const int nn = (n0 & (N_ - 1)) + lg * 4;
  if (p < 2) {
    u16* ob = p == 0 ? qb : kb;
    const float sc = p == 0 ? QSCALE : 1.0f;
#pragma unroll
    for (int ct = 0; ct < 4; ++ct) {
      const int c = c0 + ct * 16 + lr;
      const float bb = bias[c];
      const int hh = c >> 5, dd = c & 31;
#pragma unroll
      for (int j = 0; j < 4; ++j)
        ob[((size_t)(bidx * H_ + hh) * N_ + nn + j) * DH_ + dd] =
            f2bf((acc[ct][j] + bb) * sc);
    }
  } else {
#pragma unroll
    for (int ct = 0; ct < 4; ++ct) {
      const int c = c0 + ct * 16 + lr;
      const float bb = bias[c];
      const int hh = c >> 5, dd = c & 31;
#pragma unroll
      for (int j = 0; j < 4; ++j)
        vtb[((size_t)(bidx * H_ + hh) * DH_ + dd) * M_ + nn + j] =
            f2bf(acc[ct][j] + bb);
    }
  }
}

// ---------- K2: flash attention (no-max, key-split 2, XCD-swizzled) ----------
// Round-7 structure; changes: XCD-bijective decode (same-slice blocks share an
// XCD L2), presence staged once to LDS, mask as p = pr*exp2(s) (exact).
__global__ __launch_bounds__(256, 4) void attn_kernel(
    const u16* __restrict__ qb, const u16* __restrict__ kb,
    const u16* __restrict__ vtb, const float* __restrict__ presence,
    float* __restrict__ opart, float* __restrict__ lpart) {
  __shared__ u16 kvlds[2][4096];  // [buf]: K[64 keys][32 d] swz | V[32 d][64 keys] swz
  __shared__ u16 plds[4][1024];   // per-wave P tile [16 q][64 k], swizzled
  __shared__ float prlds[1024];   // presence slice (f32)
  const int t = threadIdx.x;
  const int wv = t >> 6, lane = t & 63;
  const int lr = lane & 15, lg = lane >> 4;
  // bijective XCD swizzle: slice S = (g&7)*4 + ((g>>3)&3), qblk = g>>5
  const int g = blockIdx.x;
  const int S = (g & 7) * 4 + ((g >> 3) & 3);
  const int qblk = g >> 5;
  const int s = S >> 4, bh = S & 15;
  const int b = bh >> 3, h = bh & 7;
  const int n0 = qblk * 64 + wv * 16;
  const int m0 = s * (M_ / SPLITS);
  const int NI = (M_ / SPLITS) / 64;  // 16 chunks

  // staging sources (per-lane, pre-swizzled). Each thread: one 16B K piece
  // (key = t>>2, slot t&3, swz (key>>1)&3) and one 16B V piece (d = t>>3,
  // slot t&7, swz d&7).
  const int gsk = (t & 3) ^ ((t >> 3) & 3);
  const u16* kst = kb + ((size_t)bh * M_ + m0 + (t >> 2)) * DH_ + gsk * 8;
  const int gsv = (t & 7) ^ ((t >> 3) & 7);
  const u16* vst = vtb + ((size_t)bh * DH_ + (t >> 3)) * M_ + m0 + gsv * 8;
  u16* const ldswK = &kvlds[0][0] + wv * 512;         // + buf*4096
  u16* const ldswV = &kvlds[0][0] + 2048 + wv * 512;  // + buf*4096

  // per-lane LDS fragment read offsets (u16 units)
  const int ko0 = lr * 32 + (lg ^ ((lr >> 1) & 3)) * 8;  // K: + tt*512
  const int sw = lr & 7;
  const int vo0 = (lg ^ sw) * 8;        // keys lg*8
  const int vo1 = ((4 + lg) ^ sw) * 8;  // keys 32+lg*8

  // Q as B-frag of S^T: col=query=lr, k=d=lg*8+j
  const short8 qf = *(const short8*)(qb + ((size_t)bh * N_ + n0 + lr) * DH_ + lg * 8);
  u16* const plw = plds[wv] + lr * 64;

  const f32x4 zz = {0.f, 0.f, 0.f, 0.f};
  f32x4 o0 = zz, o1 = zz, racc = zz;

  gload_lds16(kst, ldswK);  // chunk 0 -> buf 0
  gload_lds16(vst, ldswV);
  gload_lds16f(presence + (size_t)b * M_ + m0 + wv * 256 + lane * 4, prlds + wv * 256);
  __syncthreads();

#pragma unroll 2
  for (int i = 0; i < NI; ++i) {
    const int mm = i * 64;
    const u16* kl = &kvlds[i & 1][0];
    const u16* vl = &kvlds[i & 1][2048];
    if (i + 1 < NI) {  // prefetch chunk i+1 into other buffer
      const int bo = ((i + 1) & 1) * 4096;
      gload_lds16(kst + (size_t)(i + 1) * (64 * DH_), ldswK + bo);
      gload_lds16(vst + (size_t)(i + 1) * 64, ldswV + bo);
    }

    f32x4 s4[4];
    __builtin_amdgcn_s_setprio(1);
#pragma unroll
    for (int tt = 0; tt < 4; ++tt) {
      const short8 kf = *(const short8*)(kl + tt * 512 + ko0);
      s4[tt] = __builtin_amdgcn_mfma_f32_16x16x32_bf16(kf, qf, zz, 0, 0, 0);
    }
    __builtin_amdgcn_s_setprio(0);

#pragma unroll
    for (int tt = 0; tt < 4; ++tt) {
      const f32x4 pr = *(const f32x4*)(prlds + mm + tt * 16 + lg * 4);  // broadcast
#pragma unroll
      for (int j = 0; j < 4; ++j) s4[tt][j] = EXP2(s4[tt][j]);
      s4[tt] *= pr;  // exact 0 when masked, identity when present
      racc += s4[tt];
      const int slot = (2 * tt + (lg >> 1)) ^ sw;
      *(uint2*)(plw + slot * 8 + (lg & 1) * 4) =
          make_uint2(cvtpk_bf16(s4[tt][0], s4[tt][1]), cvtpk_bf16(s4[tt][2], s4[tt][3]));
    }
    // immediate PV (wave-private P tile; compiler orders via lgkmcnt)
    const short8 pf0 = *(const short8*)(plw + vo0);
    const short8 pf1 = *(const short8*)(plw + vo1);
    const short8 vf0 = *(const short8*)(vl + lr * 64 + vo0);
    const short8 vf1 = *(const short8*)(vl + lr * 64 + vo1);
    const short8 vf2 = *(const short8*)(vl + (16 + lr) * 64 + vo0);
    const short8 vf3 = *(const short8*)(vl + (16 + lr) * 64 + vo1);
    __builtin_amdgcn_s_setprio(1);
    o0 = __builtin_amdgcn_mfma_f32_16x16x32_bf16(pf0, vf0, o0, 0, 0, 0);
    o0 = __builtin_amdgcn_mfma_f32_16x16x32_bf16(pf1, vf1, o0, 0, 0, 0);
    o1 = __builtin_amdgcn_mfma_f32_16x16x32_bf16(pf0, vf2, o1, 0, 0, 0);
    o1 = __builtin_amdgcn_mfma_f32_16x16x32_bf16(pf1, vf3, o1, 0, 0, 0);
    __builtin_amdgcn_s_setprio(0);
    __syncthreads();
  }

  float l = (racc[0] + racc[1]) + (racc[2] + racc[3]);
  l += __shfl_xor(l, 16);
  l += __shfl_xor(l, 32);
  if (lg == 0) lpart[((size_t)s * (B_ * N_) + b * N_ + n0 + lr) * H_ + h] = l;

  float* ob = opart + ((size_t)s * (B_ * N_) + (size_t)b * N_ + n0) * D_ + h * DH_;
#pragma unroll
  for (int j = 0; j < 4; ++j) {
    const int q = lg * 4 + j;
    ob[(size_t)q * D_ + lr] = o0[j];
    ob[(size_t)q * D_ + 16 + lr] = o1[j];
  }
}

// ---------- K3: output projection: combine+normalize staged, Wo^T from global ----
__global__ __launch_bounds__(256, 4) void projo_kernel(
    const float* __restrict__ opart, const float* __restrict__ lpart,
    const u16* __restrict__ wTo, const float* __restrict__ bo,
    float* __restrict__ out) {
  __shared__ u16 xs[16 * 256];  // normalized A [n][k] bf16, swizzled
  const int n0 = blockIdx.x * 16;
  const int t = threadIdx.x;

  {  // stage A = (opart0 + opart1) * (1/l): per thread 16 k of one row
    const int nL = t >> 4, kc = (t & 15) * 16;
    const int gn = n0 + nL;
    const float* o0p = opart + (size_t)gn * D_ + kc;
    const float* o1p = o0p + (size_t)(B_ * N_) * D_;
    const int h0 = kc >> 5;
    const float il = 1.f / (lpart[(size_t)gn * H_ + h0] +
                            lpart[((size_t)(B_ * N_) + gn) * H_ + h0]);
#pragma unroll
    for (int m = 0; m < 2; ++m) {
      f32x4 a = *(const f32x4*)(o0p + 8 * m) + *(const f32x4*)(o1p + 8 * m);
      f32x4 b2 = *(const f32x4*)(o0p + 8 * m + 4) + *(const f32x4*)(o1p + 8 * m + 4);
      a *= il;
      b2 *= il;
      uint4 v;
      v.x = cvtpk_bf16(a[0], a[1]);
      v.y = cvtpk_bf16(a[2], a[3]);
      v.z = cvtpk_bf16(b2[0], b2[1]);
      v.w = cvtpk_bf16(b2[2], b2[3]);
      const int k0 = kc + 8 * m;
      *(uint4*)(xs + nL * 256 + (((k0 >> 3) ^ (nL & 7)) * 8)) = v;
    }
  }
  __syncthreads();

  const int wv = t >> 6, lane = t & 63, lr = lane & 15, lg = lane >> 4;
  const int c0 = wv * 64;
  const f32x4 zz = {0.f, 0.f, 0.f, 0.f};
  f32x4 acc[4] = {zz, zz, zz, zz};
#pragma unroll
  for (int ks = 0; ks < 8; ++ks) {
    const short8 a = *(const short8*)(xs + lr * 256 + (((ks * 4 + lg) ^ (lr & 7)) * 8));
#pragma unroll
    for (int ct = 0; ct < 4; ++ct) {
      const short8 b = *(const short8*)(wTo + (size_t)(c0 + ct * 16 + lr) * D_ + ks * 32 + lg * 8);
      acc[ct] = __builtin_amdgcn_mfma_f32_16x16x32_bf16(a, b, acc[ct], 0, 0, 0);
    }
  }
  // C layout: col(lr)=c, row(lg*4+j)=n -> coalesced f32 stores
#pragma unroll
  for (int ct = 0; ct < 4; ++ct) {
    const int c = c0 + ct * 16 + lr;
    const float bb = bo[c];
#pragma unroll
    for (int j = 0; j < 4; ++j)
      out[(size_t)(n0 + lg * 4 + j) * D_ + c] = acc[ct][j] + bb;
  }
}

extern "C" void kernel_launch(void* const* d_in, const int* in_sizes, int n_in,
                              void* d_out, int out_size, void* d_ws, size_t ws_size,
                              hipStream_t stream) {
  (void)in_sizes; (void)n_in; (void)out_size; (void)ws_size;
  const float* queries  = (const float*)d_in[0];
  const float* keys     = (const float*)d_in[1];
  const float* values   = (const float*)d_in[2];
  const float* presence = (const float*)d_in[3];
  const float* Wq = (const float*)d_in[4];
  const float* bq = (const float*)d_in[5];
  const float* Wk = (const float*)d_in[6];
  const float* bk = (const float*)d_in[7];
  const float* Wv = (const float*)d_in[8];
  const float* bv = (const float*)d_in[9];
  const float* Wo = (const float*)d_in[10];
  const float* bo = (const float*)d_in[11];

  // ws: wT x4 (0.5MB) | qb 2MB | kb 2MB | vtb 2MB | opart 8MB | lpart 256KB
  u16* wTq = (u16*)d_ws;
  u16* wTk = wTq + 65536;
  u16* wTv = wTk + 65536;
  u16* wTo = wTv + 65536;
  u16* qb  = wTo + 65536;
  u16* kb  = qb + (size_t)B_ * H_ * N_ * DH_;
  u16* vtb = kb + (size_t)B_ * H_ * M_ * DH_;
  float* opart = (float*)(vtb + (size_t)B_ * H_ * DH_ * M_);
  float* lpart = opart + (size_t)SPLITS * B_ * N_ * D_;

  wtconv_kernel<<<64, 256, 0, stream>>>(Wq, Wk, Wv, Wo, wTq, wTk, wTv, wTo);
  qkvproj_kernel<<<dim3(256, 3), 256, 0, stream>>>(
      queries, keys, values, wTq, wTk, wTv, bq, bk, bv, qb, kb, vtb);
  attn_kernel<<<SPLITS * 16 * 32, 256, 0, stream>>>(qb, kb, vtb, presence, opart, lpart);
  projo_kernel<<<256, 256, 0, stream>>>(opart, lpart, wTo, bo, (float*)d_out);
}

// Round 9
// 52.288 us; speedup vs baseline: 1.0449x; 1.0449x over previous
//
#include <hip/hip_runtime.h>

#define B_ 2
#define N_ 2048
#define M_ 2048
#define D_ 256
#define H_ 8
#define DH_ 32
#define SPLITS 2
// 1/sqrt(32) * log2(e): fold into q projection; attention works in exp2 domain
#define QSCALE (0.17677669529663689f * 1.4426950408889634f)

typedef __attribute__((ext_vector_type(8))) short short8;
typedef __attribute__((ext_vector_type(4))) float f32x4;
typedef unsigned short u16;
typedef unsigned int u32;

#if __has_builtin(__builtin_amdgcn_exp2f)
#define EXP2 __builtin_amdgcn_exp2f
#else
#define EXP2 exp2f
#endif

__device__ __forceinline__ u16 f2bf(float f) {
  u32 u = __float_as_uint(f);
  return (u16)((u + 0x7fffu + ((u >> 16) & 1u)) >> 16);  // RNE
}
__device__ __forceinline__ u32 cvtpk_bf16(float lo, float hi) {
  u32 r;
  asm("v_cvt_pk_bf16_f32 %0, %1, %2" : "=v"(r) : "v"(lo), "v"(hi));
  return r;
}
__device__ __forceinline__ void gload_lds16(const u16* g, u16* l) {
  __builtin_amdgcn_global_load_lds((const __attribute__((address_space(1))) void*)g,
                                   (__attribute__((address_space(3))) void*)l, 16, 0, 0);
}
__device__ __forceinline__ void gload_lds16f(const float* g, float* l) {
  __builtin_amdgcn_global_load_lds((const __attribute__((address_space(1))) void*)g,
                                   (__attribute__((address_space(3))) void*)l, 16, 0, 0);
}

// ---------- K0: W (f32 [k][c]) -> PRE-SWIZZLED W^T (bf16 [c][slot^(c&7)]) ----------
// Output byte-layout == the LDS image the GEMM kernels want: row c (512B) holds
// k-slot sl (16B = 8 bf16) at position sl ^ (c&7). GEMM blocks DMA it linearly.
__global__ __launch_bounds__(256) void wtconv_kernel(
    const float* __restrict__ Wq, const float* __restrict__ Wk,
    const float* __restrict__ Wv, const float* __restrict__ Wo,
    u16* __restrict__ wTq, u16* __restrict__ wTk, u16* __restrict__ wTv,
    u16* __restrict__ wTo) {
  __shared__ u16 sh[64][72];
  const int blk = blockIdx.x;
  const int mi = blk >> 4, tile = blk & 15;
  const float* Ws = mi == 0 ? Wq : mi == 1 ? Wk : mi == 2 ? Wv : Wo;
  u16* Wd = mi == 0 ? wTq : mi == 1 ? wTk : mi == 2 ? wTv : wTo;
  const int r0 = (tile >> 2) * 64, c0 = (tile & 3) * 64;
  const int r = threadIdx.x & 63, qt = threadIdx.x >> 6;
  const float* sp = Ws + (size_t)(r0 + r) * D_ + c0 + qt * 16;
  u32 w[8];
#pragma unroll
  for (int i = 0; i < 4; ++i) {
    f32x4 v = *(const f32x4*)(sp + i * 4);
    w[i * 2 + 0] = cvtpk_bf16(v[0], v[1]);
    w[i * 2 + 1] = cvtpk_bf16(v[2], v[3]);
  }
  *(uint4*)(&sh[r][qt * 16]) = *(uint4*)&w[0];
  *(uint4*)(&sh[r][qt * 16 + 8]) = *(uint4*)&w[4];
  __syncthreads();
  const int cc = threadIdx.x & 63;
  u32 t2[8];
#pragma unroll
  for (int i = 0; i < 8; ++i) {
    u32 lo = sh[qt * 16 + 2 * i][cc];
    u32 hi = sh[qt * 16 + 2 * i + 1][cc];
    t2[i] = lo | (hi << 16);
  }
  const int crow = c0 + cc;
  u16* rowb = Wd + (size_t)crow * D_;
  const int sl0 = (r0 + qt * 16) >> 3;  // even
  *(uint4*)(rowb + ((sl0 ^ (crow & 7)) * 8)) = *(uint4*)&t2[0];
  *(uint4*)(rowb + (((sl0 + 1) ^ (crow & 7)) * 8)) = *(uint4*)&t2[4];
}

// ---------- K1: q/k/v projection: X staged bf16 (swizzled), W^T DMA'd ----------
// block = 32 n-rows x 64 c-cols, 4 waves (wave = 16c x 32n). grid (512, 3).
__global__ __launch_bounds__(256, 3) void qkvproj_kernel(
    const float* __restrict__ Xq, const float* __restrict__ Xk, const float* __restrict__ Xv,
    const u16* __restrict__ wTq, const u16* __restrict__ wTk, const u16* __restrict__ wTv,
    const float* __restrict__ bq, const float* __restrict__ bk, const float* __restrict__ bv,
    u16* __restrict__ qb, u16* __restrict__ kb, u16* __restrict__ vtb) {
  __shared__ u16 wsT[64 * 256];  // W^T slice, pre-swizzled image (32KB via DMA)
  __shared__ u16 xs[32 * 256];   // X [n][k] bf16, swizzle (k>>3)^(n&7)
  const int p = blockIdx.y;
  const int nb = blockIdx.x & 127, cb = blockIdx.x >> 7;
  const int n0B = nb * 32, c0B = cb * 64;
  const float* X = p == 0 ? Xq : (p == 1 ? Xk : Xv);
  const u16* wT = p == 0 ? wTq : (p == 1 ? wTk : wTv);
  const float* bias = p == 0 ? bq : (p == 1 ? bk : bv);
  const int t = threadIdx.x;
  const int wv = t >> 6, lane = t & 63, lr = lane & 15, lg = lane >> 4;

  {  // DMA W^T slice: rows c0B..c0B+63 are 32KB contiguous; 8 x 1KB per wave
    const u16* wsrc = wT + (size_t)c0B * D_ + lane * 8;
#pragma unroll
    for (int i = 0; i < 8; ++i)
      gload_lds16(wsrc + (wv * 8 + i) * 512, wsT + (wv * 8 + i) * 512);
  }
  {  // stage X: thread -> row t>>3, k (t&7)*32 .. +31
    const int nL = t >> 3, kc = (t & 7) * 32;
    const float* xp = X + (size_t)(n0B + nL) * D_ + kc;
#pragma unroll
    for (int m = 0; m < 4; ++m) {
      const f32x4 a = *(const f32x4*)(xp + 8 * m);
      const f32x4 b2 = *(const f32x4*)(xp + 8 * m + 4);
      uint4 v;
      v.x = cvtpk_bf16(a[0], a[1]);
      v.y = cvtpk_bf16(a[2], a[3]);
      v.z = cvtpk_bf16(b2[0], b2[1]);
      v.w = cvtpk_bf16(b2[2], b2[3]);
      const int k0 = kc + 8 * m;
      *(uint4*)(xs + nL * 256 + (((k0 >> 3) ^ (nL & 7)) * 8)) = v;
    }
  }
  __syncthreads();

  const f32x4 zz = {0.f, 0.f, 0.f, 0.f};
  f32x4 acc[2] = {zz, zz};
  const int arow = wv * 16 + lr;  // c within slice
#pragma unroll
  for (int ks = 0; ks < 8; ++ks) {
    const short8 a = *(const short8*)(wsT + arow * 256 + (((ks * 4 + lg) ^ (arow & 7)) * 8));
#pragma unroll
    for (int ng = 0; ng < 2; ++ng) {
      const int brow = ng * 16 + lr;
      const short8 b = *(const short8*)(xs + brow * 256 + (((ks * 4 + lg) ^ (brow & 7)) * 8));
      acc[ng] = __builtin_amdgcn_mfma_f32_16x16x32_bf16(a, b, acc[ng], 0, 0, 0);
    }
  }

  // D layout: col(lr)=n, row(lg*4+j)=c
  const int cg4 = c0B + wv * 16 + lg * 4;
  const f32x4 bias4 = *(const f32x4*)(bias + cg4);
  if (p < 2) {
    u16* ob = p == 0 ? qb : kb;
    const float sc = p == 0 ? QSCALE : 1.0f;
#pragma unroll
    for (int ng = 0; ng < 2; ++ng) {
      const int n = n0B + ng * 16 + lr;
      const int b = n >> 11, nn = n & (N_ - 1);
#pragma unroll
      for (int j = 0; j < 4; ++j) {
        const int c = cg4 + j;
        ob[((size_t)(b * H_ + (c >> 5)) * N_ + nn) * DH_ + (c & 31)] =
            f2bf((acc[ng][j] + bias4[j]) * sc);
      }
    }
  } else {
#pragma unroll
    for (int ng = 0; ng < 2; ++ng) {
      const int n = n0B + ng * 16 + lr;
      const int b = n >> 11, nn = n & (M_ - 1);
#pragma unroll
      for (int j = 0; j < 4; ++j) {
        const int c = cg4 + j;
        vtb[((size_t)(b * H_ + (c >> 5)) * DH_ + (c & 31)) * M_ + nn] =
            f2bf(acc[ng][j] + bias4[j]);
      }
    }
  }
}

// ---------- K2: flash attention (no-max, key-split 2; r7 structure + LDS presence) ----
__global__ __launch_bounds__(256, 4) void attn_kernel(
    const u16* __restrict__ qb, const u16* __restrict__ kb,
    const u16* __restrict__ vtb, const float* __restrict__ presence,
    float* __restrict__ opart, float* __restrict__ lpart) {
  __shared__ u16 kvlds[2][4096];  // [buf]: K[64 keys][32 d] swz | V[32 d][64 keys] swz
  __shared__ u16 plds[4][1024];   // per-wave P tile [16 q][64 k], swizzled
  __shared__ float prlds[1024];   // presence slice (f32)
  const int t = threadIdx.x;
  const int wv = t >> 6, lane = t & 63;
  const int lr = lane & 15, lg = lane >> 4;
  const int s = blockIdx.x >> 9;
  const int bh = (blockIdx.x >> 5) & 15;
  const int qblk = blockIdx.x & 31;
  const int b = bh >> 3, h = bh & 7;
  const int n0 = qblk * 64 + wv * 16;
  const int m0 = s * (M_ / SPLITS);
  const int NI = (M_ / SPLITS) / 64;  // 16 chunks

  // staging sources (per-lane, pre-swizzled)
  const int gsk = (t & 3) ^ ((t >> 3) & 3);
  const u16* kst = kb + ((size_t)bh * M_ + m0 + (t >> 2)) * DH_ + gsk * 8;
  const int gsv = (t & 7) ^ ((t >> 3) & 7);
  const u16* vst = vtb + ((size_t)bh * DH_ + (t >> 3)) * M_ + m0 + gsv * 8;
  u16* const ldswK = &kvlds[0][0] + wv * 512;         // + buf*4096
  u16* const ldswV = &kvlds[0][0] + 2048 + wv * 512;  // + buf*4096

  // per-lane LDS fragment read offsets (u16 units)
  const int ko0 = lr * 32 + (lg ^ ((lr >> 1) & 3)) * 8;  // K: + tt*512
  const int sw = lr & 7;
  const int vo0 = (lg ^ sw) * 8;        // keys lg*8
  const int vo1 = ((4 + lg) ^ sw) * 8;  // keys 32+lg*8

  // Q as B-frag of S^T: col=query=lr, k=d=lg*8+j
  const short8 qf = *(const short8*)(qb + ((size_t)bh * N_ + n0 + lr) * DH_ + lg * 8);
  u16* const plw = plds[wv] + lr * 64;

  const f32x4 zz = {0.f, 0.f, 0.f, 0.f};
  f32x4 o0 = zz, o1 = zz, racc = zz;

  gload_lds16(kst, ldswK);  // chunk 0 -> buf 0
  gload_lds16(vst, ldswV);
  gload_lds16f(presence + (size_t)b * M_ + m0 + wv * 256 + lane * 4, prlds + wv * 256);
  __syncthreads();

#pragma unroll 2
  for (int i = 0; i < NI; ++i) {
    const int mm = i * 64;
    const u16* kl = &kvlds[i & 1][0];
    const u16* vl = &kvlds[i & 1][2048];
    if (i + 1 < NI) {  // prefetch chunk i+1 into other buffer
      const int bo = ((i + 1) & 1) * 4096;
      gload_lds16(kst + (size_t)(i + 1) * (64 * DH_), ldswK + bo);
      gload_lds16(vst + (size_t)(i + 1) * 64, ldswV + bo);
    }

    f32x4 s4[4];
    __builtin_amdgcn_s_setprio(1);
#pragma unroll
    for (int tt = 0; tt < 4; ++tt) {
      const short8 kf = *(const short8*)(kl + tt * 512 + ko0);
      s4[tt] = __builtin_amdgcn_mfma_f32_16x16x32_bf16(kf, qf, zz, 0, 0, 0);
    }
    __builtin_amdgcn_s_setprio(0);

#pragma unroll
    for (int tt = 0; tt < 4; ++tt) {
      const f32x4 pr = *(const f32x4*)(prlds + mm + tt * 16 + lg * 4);  // broadcast
#pragma unroll
      for (int j = 0; j < 4; ++j) s4[tt][j] = EXP2(s4[tt][j]);
      s4[tt] *= pr;  // exact 0 when masked, identity when present
      racc += s4[tt];
      const int slot = (2 * tt + (lg >> 1)) ^ sw;
      *(uint2*)(plw + slot * 8 + (lg & 1) * 4) =
          make_uint2(cvtpk_bf16(s4[tt][0], s4[tt][1]), cvtpk_bf16(s4[tt][2], s4[tt][3]));
    }
    // immediate PV (wave-private P tile; compiler orders via lgkmcnt)
    const short8 pf0 = *(const short8*)(plw + vo0);
    const short8 pf1 = *(const short8*)(plw + vo1);
    const short8 vf0 = *(const short8*)(vl + lr * 64 + vo0);
    const short8 vf1 = *(const short8*)(vl + lr * 64 + vo1);
    const short8 vf2 = *(const short8*)(vl + (16 + lr) * 64 + vo0);
    const short8 vf3 = *(const short8*)(vl + (16 + lr) * 64 + vo1);
    __builtin_amdgcn_s_setprio(1);
    o0 = __builtin_amdgcn_mfma_f32_16x16x32_bf16(pf0, vf0, o0, 0, 0, 0);
    o0 = __builtin_amdgcn_mfma_f32_16x16x32_bf16(pf1, vf1, o0, 0, 0, 0);
    o1 = __builtin_amdgcn_mfma_f32_16x16x32_bf16(pf0, vf2, o1, 0, 0, 0);
    o1 = __builtin_amdgcn_mfma_f32_16x16x32_bf16(pf1, vf3, o1, 0, 0, 0);
    __builtin_amdgcn_s_setprio(0);
    __syncthreads();
  }

  float l = (racc[0] + racc[1]) + (racc[2] + racc[3]);
  l += __shfl_xor(l, 16);
  l += __shfl_xor(l, 32);
  if (lg == 0) lpart[((size_t)s * (B_ * N_) + b * N_ + n0 + lr) * H_ + h] = l;

  float* ob = opart + ((size_t)s * (B_ * N_) + (size_t)b * N_ + n0) * D_ + h * DH_;
#pragma unroll
  for (int j = 0; j < 4; ++j) {
    const int q = lg * 4 + j;
    ob[(size_t)q * D_ + lr] = o0[j];
    ob[(size_t)q * D_ + 16 + lr] = o1[j];
  }
}

// ---------- K3: output projection: combine+normalize staged, Wo^T DMA'd ----------
// block = 32 n x 64 c, 4 waves (wave = 16n x 32c). grid 512.
__global__ __launch_bounds__(256, 3) void projo_kernel(
    const float* __restrict__ opart, const float* __restrict__ lpart,
    const u16* __restrict__ wTo, const float* __restrict__ bo,
    float* __restrict__ out) {
  __shared__ u16 ws[64 * 256];  // Wo^T slice, pre-swizzled image (32KB via DMA)
  __shared__ u16 xs[32 * 256];  // normalized A [n][k], swizzle (k>>3)^(n&7)
  const int nb = blockIdx.x & 127, cb = blockIdx.x >> 7;
  const int n0B = nb * 32, c0B = cb * 64;
  const int t = threadIdx.x;
  const int wv = t >> 6, lane = t & 63, lr = lane & 15, lg = lane >> 4;

  {  // DMA Wo^T slice
    const u16* wsrc = wTo + (size_t)c0B * D_ + lane * 8;
#pragma unroll
    for (int i = 0; i < 8; ++i)
      gload_lds16(wsrc + (wv * 8 + i) * 512, ws + (wv * 8 + i) * 512);
  }
  {  // stage A = (opart0 + opart1) * (1/l)
    const int nL = t >> 3, kc = (t & 7) * 32;
    const int gn = n0B + nL;
    const float* o0p = opart + (size_t)gn * D_ + kc;
    const float* o1p = o0p + (size_t)(B_ * N_) * D_;
    const int h0 = kc >> 5;
    const float il = 1.f / (lpart[(size_t)gn * H_ + h0] +
                            lpart[((size_t)(B_ * N_) + gn) * H_ + h0]);
#pragma unroll
    for (int m = 0; m < 4; ++m) {
      f32x4 a = *(const f32x4*)(o0p + 8 * m) + *(const f32x4*)(o1p + 8 * m);
      f32x4 b2 = *(const f32x4*)(o0p + 8 * m + 4) + *(const f32x4*)(o1p + 8 * m + 4);
      a *= il;
      b2 *= il;
      uint4 v;
      v.x = cvtpk_bf16(a[0], a[1]);
      v.y = cvtpk_bf16(a[2], a[3]);
      v.z = cvtpk_bf16(b2[0], b2[1]);
      v.w = cvtpk_bf16(b2[2], b2[3]);
      const int k0 = kc + 8 * m;
      *(uint4*)(xs + nL * 256 + (((k0 >> 3) ^ (nL & 7)) * 8)) = v;
    }
  }
  __syncthreads();

  const f32x4 zz = {0.f, 0.f, 0.f, 0.f};
  f32x4 acc[2] = {zz, zz};
  const int arow = (wv & 1) * 16 + lr;   // n within tile
  const int cw0 = (wv >> 1) * 32;        // wave's c-half
#pragma unroll
  for (int ks = 0; ks < 8; ++ks) {
    const short8 a = *(const short8*)(xs + arow * 256 + (((ks * 4 + lg) ^ (arow & 7)) * 8));
#pragma unroll
    for (int ng = 0; ng < 2; ++ng) {
      const int brow = cw0 + ng * 16 + lr;
      const short8 b = *(const short8*)(ws + brow * 256 + (((ks * 4 + lg) ^ (brow & 7)) * 8));
      acc[ng] = __builtin_amdgcn_mfma_f32_16x16x32_bf16(a, b, acc[ng], 0, 0, 0);
    }
  }
  // D layout: col(lr)=c, row(lg*4+j)=n -> coalesced f32 stores
#pragma unroll
  for (int ng = 0; ng < 2; ++ng) {
    const int c = c0B + cw0 + ng * 16 + lr;
    const float bb = bo[c];
#pragma unroll
    for (int j = 0; j < 4; ++j)
      out[(size_t)(n0B + (wv & 1) * 16 + lg * 4 + j) * D_ + c] = acc[ng][j] + bb;
  }
}

extern "C" void kernel_launch(void* const* d_in, const int* in_sizes, int n_in,
                              void* d_out, int out_size, void* d_ws, size_t ws_size,
                              hipStream_t stream) {
  (void)in_sizes; (void)n_in; (void)out_size; (void)ws_size;
  const float* queries  = (const float*)d_in[0];
  const float* keys     = (const float*)d_in[1];
  const float* values   = (const float*)d_in[2];
  const float* presence = (const float*)d_in[3];
  const float* Wq = (const float*)d_in[4];
  const float* bq = (const float*)d_in[5];
  const float* Wk = (const float*)d_in[6];
  const float* bk = (const float*)d_in[7];
  const float* Wv = (const float*)d_in[8];
  const float* bv = (const float*)d_in[9];
  const float* Wo = (const float*)d_in[10];
  const float* bo = (const float*)d_in[11];

  // ws: wT x4 (0.5MB) | qb 2MB | kb 2MB | vtb 2MB | opart 8MB | lpart 256KB
  u16* wTq = (u16*)d_ws;
  u16* wTk = wTq + 65536;
  u16* wTv = wTk + 65536;
  u16* wTo = wTv + 65536;
  u16* qb  = wTo + 65536;
  u16* kb  = qb + (size_t)B_ * H_ * N_ * DH_;
  u16* vtb = kb + (size_t)B_ * H_ * M_ * DH_;
  float* opart = (float*)(vtb + (size_t)B_ * H_ * DH_ * M_);
  float* lpart = opart + (size_t)SPLITS * B_ * N_ * D_;

  wtconv_kernel<<<64, 256, 0, stream>>>(Wq, Wk, Wv, Wo, wTq, wTk, wTv, wTo);
  qkvproj_kernel<<<dim3(512, 3), 256, 0, stream>>>(
      queries, keys, values, wTq, wTk, wTv, bq, bk, bv, qb, kb, vtb);
  attn_kernel<<<SPLITS * 16 * 32, 256, 0, stream>>>(qb, kb, vtb, presence, opart, lpart);
  projo_kernel<<<512, 256, 0, stream>>>(opart, lpart, wTo, bo, (float*)d_out);
}

// Round 10
// 49.438 us; speedup vs baseline: 1.1051x; 1.0577x over previous
//
#include <hip/hip_runtime.h>

#define B_ 2
#define N_ 2048
#define M_ 2048
#define D_ 256
#define H_ 8
#define DH_ 32
#define SPLITS 4
// 1/sqrt(32) * log2(e): fold into q projection; attention works in exp2 domain
#define QSCALE (0.17677669529663689f * 1.4426950408889634f)

typedef __attribute__((ext_vector_type(8))) short short8;
typedef __attribute__((ext_vector_type(4))) float f32x4;
typedef unsigned short u16;
typedef unsigned int u32;

#if __has_builtin(__builtin_amdgcn_exp2f)
#define EXP2 __builtin_amdgcn_exp2f
#else
#define EXP2 exp2f
#endif

__device__ __forceinline__ u16 f2bf(float f) {
  u32 u = __float_as_uint(f);
  return (u16)((u + 0x7fffu + ((u >> 16) & 1u)) >> 16);  // RNE
}
__device__ __forceinline__ u32 cvtpk_bf16(float lo, float hi) {
  u32 r;
  asm("v_cvt_pk_bf16_f32 %0, %1, %2" : "=v"(r) : "v"(lo), "v"(hi));
  return r;
}
__device__ __forceinline__ void gload_lds16(const u16* g, u16* l) {
  __builtin_amdgcn_global_load_lds((const __attribute__((address_space(1))) void*)g,
                                   (__attribute__((address_space(3))) void*)l, 16, 0, 0);
}
__device__ __forceinline__ void gload_lds16f(const float* g, float* l) {
  __builtin_amdgcn_global_load_lds((const __attribute__((address_space(1))) void*)g,
                                   (__attribute__((address_space(3))) void*)l, 16, 0, 0);
}

// ---------- K1: fused q/k/v projection (r7 version, best measured) ----------
// block = 64 c x 64 n, 4 waves. W transpose-converted to LDS bf16 (swizzled);
// X converted to LDS bf16 (swizzled). Outputs: q/k [bh][n][32] (q * QSCALE),
// v transposed [bh][32][M].
__global__ __launch_bounds__(256, 2) void qkvproj_kernel(
    const float* __restrict__ Xq, const float* __restrict__ Xk, const float* __restrict__ Xv,
    const float* __restrict__ Wq, const float* __restrict__ Wk, const float* __restrict__ Wv,
    const float* __restrict__ bq, const float* __restrict__ bk, const float* __restrict__ bv,
    u16* __restrict__ qb, u16* __restrict__ kb, u16* __restrict__ vtb) {
  __shared__ u16 wsT[64 * 256];  // [c][k] = W[k][c], 16B-slot swizzle (k>>3)^(c&7)
  __shared__ u16 xs[64 * 256];   // [n][k] = X[n][k], swizzle (k>>3)^(n&7)
  const int p = blockIdx.y;
  const int nb = blockIdx.x & 63, cb = blockIdx.x >> 6;
  const int n0B = nb * 64, c0B = cb * 64;
  const float* X = p == 0 ? Xq : (p == 1 ? Xk : Xv);
  const float* W = p == 0 ? Wq : (p == 1 ? Wk : Wv);
  const float* bias = p == 0 ? bq : (p == 1 ? bk : bv);
  const int t = threadIdx.x;

  {  // stage W^T
    const int cL = (t & 15) * 4, kB = (t >> 4) * 16;
    const float* wp = W + (size_t)kB * D_ + c0B + cL;
#pragma unroll
    for (int u = 0; u < 4; ++u) {
      const int k0 = kB + 4 * u;
      const f32x4 w0 = *(const f32x4*)(wp + (size_t)(4 * u + 0) * D_);
      const f32x4 w1 = *(const f32x4*)(wp + (size_t)(4 * u + 1) * D_);
      const f32x4 w2 = *(const f32x4*)(wp + (size_t)(4 * u + 2) * D_);
      const f32x4 w3 = *(const f32x4*)(wp + (size_t)(4 * u + 3) * D_);
#pragma unroll
      for (int cc = 0; cc < 4; ++cc) {
        const int c = cL + cc;
        uint2 v;
        v.x = cvtpk_bf16(w0[cc], w1[cc]);
        v.y = cvtpk_bf16(w2[cc], w3[cc]);
        *(uint2*)(wsT + c * 256 + (((k0 >> 3) ^ (c & 7)) * 8) + (k0 & 7)) = v;
      }
    }
  }
  {  // stage X
    const int nL = t >> 2, k64 = (t & 3) * 64;
    const float* xp = X + (size_t)(n0B + nL) * D_ + k64;
#pragma unroll
    for (int m = 0; m < 8; ++m) {
      const f32x4 a = *(const f32x4*)(xp + 8 * m);
      const f32x4 b2 = *(const f32x4*)(xp + 8 * m + 4);
      uint4 v;
      v.x = cvtpk_bf16(a[0], a[1]);
      v.y = cvtpk_bf16(a[2], a[3]);
      v.z = cvtpk_bf16(b2[0], b2[1]);
      v.w = cvtpk_bf16(b2[2], b2[3]);
      const int k0 = k64 + 8 * m;
      *(uint4*)(xs + nL * 256 + (((k0 >> 3) ^ (nL & 7)) * 8)) = v;
    }
  }
  __syncthreads();

  const int wv = t >> 6, lane = t & 63, lr = lane & 15, lg = lane >> 4;
  const f32x4 zz = {0.f, 0.f, 0.f, 0.f};
  f32x4 acc[4] = {zz, zz, zz, zz};
  const int arow = wv * 16 + lr;
#pragma unroll
  for (int ks = 0; ks < 8; ++ks) {
    const short8 a = *(const short8*)(wsT + arow * 256 + (((ks * 4 + lg) ^ (arow & 7)) * 8));
#pragma unroll
    for (int ng = 0; ng < 4; ++ng) {
      const int brow = ng * 16 + lr;
      const short8 b = *(const short8*)(xs + brow * 256 + (((ks * 4 + lg) ^ (brow & 7)) * 8));
      acc[ng] = __builtin_amdgcn_mfma_f32_16x16x32_bf16(a, b, acc[ng], 0, 0, 0);
    }
  }

  // D layout: col(lr)=n, row(lg*4+j)=c
  const int cg4 = c0B + wv * 16 + lg * 4;
  const f32x4 bias4 = *(const f32x4*)(bias + cg4);
  if (p < 2) {
    u16* ob = p == 0 ? qb : kb;
    const float sc = p == 0 ? QSCALE : 1.0f;
#pragma unroll
    for (int ng = 0; ng < 4; ++ng) {
      const int n = n0B + ng * 16 + lr;
      const int b = n >> 11, nn = n & (N_ - 1);
#pragma unroll
      for (int j = 0; j < 4; ++j) {
        const int c = cg4 + j;
        ob[((size_t)(b * H_ + (c >> 5)) * N_ + nn) * DH_ + (c & 31)] =
            f2bf((acc[ng][j] + bias4[j]) * sc);
      }
    }
  } else {
#pragma unroll
    for (int ng = 0; ng < 4; ++ng) {
      const int n = n0B + ng * 16 + lr;
      const int b = n >> 11, nn = n & (M_ - 1);
#pragma unroll
      for (int j = 0; j < 4; ++j) {
        const int c = cg4 + j;
        vtb[((size_t)(b * H_ + (c >> 5)) * DH_ + (c & 31)) * M_ + nn] =
            f2bf(acc[ng][j] + bias4[j]);
      }
    }
  }
}

// ---------- K2: flash attention (no-max, key-split 4, 32 q-rows per wave) ----
// grid = 4 splits x 16 bh x 16 qblk = 1024 blocks (4/CU); block = 4 waves,
// 32 q each (two 16-row Q frags sharing every K/V LDS read). Per 64-key chunk:
// K/V staged once per block (global_load_lds, pre-swizzled source, dbuf,
// one-chunk prefetch); S^T = mfma(K,Q) x8; exp2 * presence (LDS-broadcast);
// P bf16 -> wave-private swizzled LDS (2 sub-tiles); PV x8. setprio (T5).
__global__ __launch_bounds__(256, 4) void attn_kernel(
    const u16* __restrict__ qb, const u16* __restrict__ kb,
    const u16* __restrict__ vtb, const float* __restrict__ presence,
    float* __restrict__ opart, float* __restrict__ lpart) {
  __shared__ u16 kvlds[2][4096];  // [buf]: K[64 keys][32 d] swz | V[32 d][64 keys] swz
  __shared__ u16 plds[4][2048];   // per-wave P tile: [frag][16 q][64 k], swizzled
  __shared__ float prlds[512];    // presence slice (f32)
  const int t = threadIdx.x;
  const int wv = t >> 6, lane = t & 63;
  const int lr = lane & 15, lg = lane >> 4;
  const int g = blockIdx.x;
  const int s = g >> 8;
  const int bh = (g >> 4) & 15;
  const int qblk = g & 15;
  const int b = bh >> 3, h = bh & 7;
  const int n0 = qblk * 128 + wv * 32;
  const int m0 = s * (M_ / SPLITS);
  const int NI = (M_ / SPLITS) / 64;  // 8 chunks

  // staging sources (per-lane, pre-swizzled)
  const int gsk = (t & 3) ^ ((t >> 3) & 3);
  const u16* kst = kb + ((size_t)bh * M_ + m0 + (t >> 2)) * DH_ + gsk * 8;
  const int gsv = (t & 7) ^ ((t >> 3) & 7);
  const u16* vst = vtb + ((size_t)bh * DH_ + (t >> 3)) * M_ + m0 + gsv * 8;
  u16* const ldswK = &kvlds[0][0] + wv * 512;         // + buf*4096
  u16* const ldswV = &kvlds[0][0] + 2048 + wv * 512;  // + buf*4096

  // per-lane LDS fragment read offsets (u16 units)
  const int ko0 = lr * 32 + (lg ^ ((lr >> 1) & 3)) * 8;  // K: + tt*512
  const int sw = lr & 7;
  const int vo0 = (lg ^ sw) * 8;        // keys lg*8
  const int vo1 = ((4 + lg) ^ sw) * 8;  // keys 32+lg*8

  // Q as B-frag of S^T: col=query=lr, k=d=lg*8+j ; two 16-row frags
  const u16* qbase = qb + ((size_t)bh * N_ + n0 + lr) * DH_ + lg * 8;
  const short8 qf0 = *(const short8*)(qbase);
  const short8 qf1 = *(const short8*)(qbase + 16 * DH_);
  u16* const plw0 = plds[wv] + lr * 64;
  u16* const plw1 = plds[wv] + 1024 + lr * 64;

  const f32x4 zz = {0.f, 0.f, 0.f, 0.f};
  f32x4 o0 = zz, o1 = zz, o2 = zz, o3 = zz, racc0 = zz, racc1 = zz;

  gload_lds16(kst, ldswK);  // chunk 0 -> buf 0
  gload_lds16(vst, ldswV);
  if (wv < 2)
    gload_lds16f(presence + (size_t)b * M_ + m0 + wv * 256 + lane * 4, prlds + wv * 256);
  __syncthreads();

#pragma unroll 2
  for (int i = 0; i < NI; ++i) {
    const int mm = i * 64;
    const u16* kl = &kvlds[i & 1][0];
    const u16* vl = &kvlds[i & 1][2048];
    if (i + 1 < NI) {  // prefetch chunk i+1 into other buffer
      const int bo = ((i + 1) & 1) * 4096;
      gload_lds16(kst + (size_t)(i + 1) * (64 * DH_), ldswK + bo);
      gload_lds16(vst + (size_t)(i + 1) * 64, ldswV + bo);
    }

    f32x4 s4a[4], s4b[4];
    __builtin_amdgcn_s_setprio(1);
#pragma unroll
    for (int tt = 0; tt < 4; ++tt) {
      const short8 kf = *(const short8*)(kl + tt * 512 + ko0);
      s4a[tt] = __builtin_amdgcn_mfma_f32_16x16x32_bf16(kf, qf0, zz, 0, 0, 0);
      s4b[tt] = __builtin_amdgcn_mfma_f32_16x16x32_bf16(kf, qf1, zz, 0, 0, 0);
    }
    __builtin_amdgcn_s_setprio(0);

#pragma unroll
    for (int tt = 0; tt < 4; ++tt) {
      const f32x4 pr = *(const f32x4*)(prlds + mm + tt * 16 + lg * 4);  // broadcast
      const int so = (((2 * tt + (lg >> 1)) ^ sw) * 8) + (lg & 1) * 4;
#pragma unroll
      for (int j = 0; j < 4; ++j) s4a[tt][j] = EXP2(s4a[tt][j]);
      s4a[tt] *= pr;  // exact 0 masked / identity present
      racc0 += s4a[tt];
      *(uint2*)(plw0 + so) =
          make_uint2(cvtpk_bf16(s4a[tt][0], s4a[tt][1]), cvtpk_bf16(s4a[tt][2], s4a[tt][3]));
#pragma unroll
      for (int j = 0; j < 4; ++j) s4b[tt][j] = EXP2(s4b[tt][j]);
      s4b[tt] *= pr;
      racc1 += s4b[tt];
      *(uint2*)(plw1 + so) =
          make_uint2(cvtpk_bf16(s4b[tt][0], s4b[tt][1]), cvtpk_bf16(s4b[tt][2], s4b[tt][3]));
    }
    // PV (wave-private P tiles; compiler orders via lgkmcnt). V reads shared.
    const short8 pf00 = *(const short8*)(plw0 + vo0);
    const short8 pf01 = *(const short8*)(plw0 + vo1);
    const short8 pf10 = *(const short8*)(plw1 + vo0);
    const short8 pf11 = *(const short8*)(plw1 + vo1);
    const short8 vf0 = *(const short8*)(vl + lr * 64 + vo0);
    const short8 vf1 = *(const short8*)(vl + lr * 64 + vo1);
    const short8 vf2 = *(const short8*)(vl + (16 + lr) * 64 + vo0);
    const short8 vf3 = *(const short8*)(vl + (16 + lr) * 64 + vo1);
    __builtin_amdgcn_s_setprio(1);
    o0 = __builtin_amdgcn_mfma_f32_16x16x32_bf16(pf00, vf0, o0, 0, 0, 0);
    o0 = __builtin_amdgcn_mfma_f32_16x16x32_bf16(pf01, vf1, o0, 0, 0, 0);
    o1 = __builtin_amdgcn_mfma_f32_16x16x32_bf16(pf00, vf2, o1, 0, 0, 0);
    o1 = __builtin_amdgcn_mfma_f32_16x16x32_bf16(pf01, vf3, o1, 0, 0, 0);
    o2 = __builtin_amdgcn_mfma_f32_16x16x32_bf16(pf10, vf0, o2, 0, 0, 0);
    o2 = __builtin_amdgcn_mfma_f32_16x16x32_bf16(pf11, vf1, o2, 0, 0, 0);
    o3 = __builtin_amdgcn_mfma_f32_16x16x32_bf16(pf10, vf2, o3, 0, 0, 0);
    o3 = __builtin_amdgcn_mfma_f32_16x16x32_bf16(pf11, vf3, o3, 0, 0, 0);
    __builtin_amdgcn_s_setprio(0);
    __syncthreads();
  }

  float l0 = (racc0[0] + racc0[1]) + (racc0[2] + racc0[3]);
  l0 += __shfl_xor(l0, 16);
  l0 += __shfl_xor(l0, 32);
  float l1 = (racc1[0] + racc1[1]) + (racc1[2] + racc1[3]);
  l1 += __shfl_xor(l1, 16);
  l1 += __shfl_xor(l1, 32);
  if (lg == 0) {
    lpart[((size_t)s * (B_ * N_) + b * N_ + n0 + lr) * H_ + h] = l0;
    lpart[((size_t)s * (B_ * N_) + b * N_ + n0 + 16 + lr) * H_ + h] = l1;
  }

  float* ob = opart + ((size_t)s * (B_ * N_) + (size_t)b * N_ + n0) * D_ + h * DH_;
#pragma unroll
  for (int j = 0; j < 4; ++j) {
    const int q = lg * 4 + j;
    ob[(size_t)q * D_ + lr] = o0[j];
    ob[(size_t)q * D_ + 16 + lr] = o1[j];
    ob[(size_t)(16 + q) * D_ + lr] = o2[j];
    ob[(size_t)(16 + q) * D_ + 16 + lr] = o3[j];
  }
}

// ---------- K3: output projection (combine 4 splits, normalize, MFMA) ----------
__global__ __launch_bounds__(256, 2) void projo_kernel(
    const float* __restrict__ opart, const float* __restrict__ lpart,
    const float* __restrict__ Wo, const float* __restrict__ bo,
    float* __restrict__ out) {
  __shared__ u16 wsT[64 * 256];  // Wo^T [c][k] swizzled
  __shared__ u16 xs[64 * 256];   // normalized attention output [n][k] swizzled
  const int nb = blockIdx.x & 63, cb = blockIdx.x >> 6;
  const int n0B = nb * 64, c0B = cb * 64;
  const int t = threadIdx.x;

  {  // stage Wo^T
    const int cL = (t & 15) * 4, kB = (t >> 4) * 16;
    const float* wp = Wo + (size_t)kB * D_ + c0B + cL;
#pragma unroll
    for (int u = 0; u < 4; ++u) {
      const int k0 = kB + 4 * u;
      const f32x4 w0 = *(const f32x4*)(wp + (size_t)(4 * u + 0) * D_);
      const f32x4 w1 = *(const f32x4*)(wp + (size_t)(4 * u + 1) * D_);
      const f32x4 w2 = *(const f32x4*)(wp + (size_t)(4 * u + 2) * D_);
      const f32x4 w3 = *(const f32x4*)(wp + (size_t)(4 * u + 3) * D_);
#pragma unroll
      for (int cc = 0; cc < 4; ++cc) {
        const int c = cL + cc;
        uint2 v;
        v.x = cvtpk_bf16(w0[cc], w1[cc]);
        v.y = cvtpk_bf16(w2[cc], w3[cc]);
        *(uint2*)(wsT + c * 256 + (((k0 >> 3) ^ (c & 7)) * 8) + (k0 & 7)) = v;
      }
    }
  }
  {  // stage A = (sum of 4 split partials) * (1/l), bf16 swizzled
    const int nL = t >> 2, k64 = (t & 3) * 64;
    const int gn = n0B + nL;
    const int h0 = k64 >> 5;
    float l0s = 0.f, l1s = 0.f;
#pragma unroll
    for (int sp = 0; sp < SPLITS; ++sp) {
      l0s += lpart[((size_t)sp * (B_ * N_) + gn) * H_ + h0];
      l1s += lpart[((size_t)sp * (B_ * N_) + gn) * H_ + h0 + 1];
    }
    const float il0 = 1.f / l0s, il1 = 1.f / l1s;
    const float* obase = opart + (size_t)gn * D_ + k64;
#pragma unroll
    for (int m = 0; m < 8; ++m) {
      f32x4 a = {0.f, 0.f, 0.f, 0.f};
      f32x4 b2 = {0.f, 0.f, 0.f, 0.f};
#pragma unroll
      for (int sp = 0; sp < SPLITS; ++sp) {
        const float* op = obase + (size_t)sp * (B_ * N_) * D_;
        a += *(const f32x4*)(op + 8 * m);
        b2 += *(const f32x4*)(op + 8 * m + 4);
      }
      const float il = (m < 4) ? il0 : il1;
      a *= il;
      b2 *= il;
      uint4 v;
      v.x = cvtpk_bf16(a[0], a[1]);
      v.y = cvtpk_bf16(a[2], a[3]);
      v.z = cvtpk_bf16(b2[0], b2[1]);
      v.w = cvtpk_bf16(b2[2], b2[3]);
      const int k0 = k64 + 8 * m;
      *(uint4*)(xs + nL * 256 + (((k0 >> 3) ^ (nL & 7)) * 8)) = v;
    }
  }
  __syncthreads();

  const int wv = t >> 6, lane = t & 63, lr = lane & 15, lg = lane >> 4;
  const f32x4 zz = {0.f, 0.f, 0.f, 0.f};
  f32x4 acc[4] = {zz, zz, zz, zz};
  const int arow = wv * 16 + lr;
#pragma unroll
  for (int ks = 0; ks < 8; ++ks) {
    const short8 a = *(const short8*)(xs + arow * 256 + (((ks * 4 + lg) ^ (arow & 7)) * 8));
#pragma unroll
    for (int ng = 0; ng < 4; ++ng) {
      const int brow = ng * 16 + lr;
      const short8 bfr = *(const short8*)(wsT + brow * 256 + (((ks * 4 + lg) ^ (brow & 7)) * 8));
      acc[ng] = __builtin_amdgcn_mfma_f32_16x16x32_bf16(a, bfr, acc[ng], 0, 0, 0);
    }
  }
  // D layout: col(lr)=c, row(lg*4+j)=n -> coalesced f32 stores
#pragma unroll
  for (int ng = 0; ng < 4; ++ng) {
    const int c = c0B + ng * 16 + lr;
    const float bb = bo[c];
#pragma unroll
    for (int j = 0; j < 4; ++j)
      out[(size_t)(n0B + wv * 16 + lg * 4 + j) * D_ + c] = acc[ng][j] + bb;
  }
}

extern "C" void kernel_launch(void* const* d_in, const int* in_sizes, int n_in,
                              void* d_out, int out_size, void* d_ws, size_t ws_size,
                              hipStream_t stream) {
  (void)in_sizes; (void)n_in; (void)out_size; (void)ws_size;
  const float* queries  = (const float*)d_in[0];
  const float* keys     = (const float*)d_in[1];
  const float* values   = (const float*)d_in[2];
  const float* presence = (const float*)d_in[3];
  const float* Wq = (const float*)d_in[4];
  const float* bq = (const float*)d_in[5];
  const float* Wk = (const float*)d_in[6];
  const float* bk = (const float*)d_in[7];
  const float* Wv = (const float*)d_in[8];
  const float* bv = (const float*)d_in[9];
  const float* Wo = (const float*)d_in[10];
  const float* bo = (const float*)d_in[11];

  // ws: qb 2MB | kb 2MB | vtb 2MB | opart 16MB | lpart 512KB
  u16* qb  = (u16*)d_ws;
  u16* kb  = qb + (size_t)B_ * H_ * N_ * DH_;
  u16* vtb = kb + (size_t)B_ * H_ * M_ * DH_;
  float* opart = (float*)(vtb + (size_t)B_ * H_ * DH_ * M_);
  float* lpart = opart + (size_t)SPLITS * B_ * N_ * D_;

  qkvproj_kernel<<<dim3(256, 3), 256, 0, stream>>>(
      queries, keys, values, Wq, Wk, Wv, bq, bk, bv, qb, kb, vtb);
  attn_kernel<<<SPLITS * 16 * 16, 256, 0, stream>>>(qb, kb, vtb, presence, opart, lpart);
  projo_kernel<<<256, 256, 0, stream>>>(opart, lpart, Wo, bo, (float*)d_out);
}